// Round 5
// baseline (299.452 us; speedup 1.0000x reference)
//
#include <hip/hip_runtime.h>
#include <hip/hip_bf16.h>
#include <cstdint>
#include <cstddef>

#define T_TOK 8192
#define H_DIM 768
#define I_DIM 1024
#define N_EXP 5
#define MAXTILE 136
#define DROWS (2 * T_TOK)   // total dense rows

typedef short v8s __attribute__((ext_vector_type(8)));
typedef float v4f __attribute__((ext_vector_type(4)));

static __device__ __forceinline__ unsigned short f2bf(float f) {
    union { float f; unsigned int u; } v; v.f = f;
    unsigned int u = v.u;
    unsigned int r = (u + 0x7fffu + ((u >> 16) & 1u)) >> 16;
    return (unsigned short)r;
}
static __device__ __forceinline__ float bf2f(unsigned short s) {
    union { unsigned int u; float f; } v; v.u = ((unsigned int)s) << 16; return v.f;
}

// async 16B global->LDS (wave-uniform LDS base + lane*16)
static __device__ __forceinline__ void async16(const unsigned short* g, unsigned short* l) {
    __builtin_amdgcn_global_load_lds(
        (const __attribute__((address_space(1))) unsigned int*)g,
        (__attribute__((address_space(3))) unsigned int*)l, 16, 0, 0);
}

// ---- merged weight transposes ----
// z in [0,10): gate/up -> wbt[e][2I][H] interleaved by 16-col groups
// z in [10,15): down   -> dbt[e][H][I]
__global__ void k_transp_all(const float* __restrict__ gw, const float* __restrict__ uw,
                             const float* __restrict__ dw,
                             unsigned short* __restrict__ wbt, unsigned short* __restrict__ dbt) {
    __shared__ float tile[32][33];
    const int z = blockIdx.z;
    const int tx = threadIdx.x, ty = threadIdx.y;
    if (z < 2 * N_EXP) {
        if (blockIdx.y >= H_DIM / 32) return;
        const int e = z % N_EXP;
        const int isUp = z >= N_EXP;
        const float* src = (isUp ? uw : gw) + (size_t)e * H_DIM * I_DIM;
        const int c0 = blockIdx.x * 32, r0 = blockIdx.y * 32;
#pragma unroll
        for (int i = 0; i < 4; i++)
            tile[ty * 4 + i][tx] = src[(size_t)(r0 + ty * 4 + i) * I_DIM + c0 + tx];
        __syncthreads();
#pragma unroll
        for (int i = 0; i < 4; i++) {
            int c = c0 + ty * 4 + i;
            int row = (c >> 4) * 32 + (c & 15) + (isUp ? 16 : 0);
            wbt[((size_t)e * 2 * I_DIM + row) * H_DIM + r0 + tx] = f2bf(tile[tx][ty * 4 + i]);
        }
    } else {
        if (blockIdx.x >= H_DIM / 32) return;
        const int e = z - 2 * N_EXP;
        const float* src = dw + (size_t)e * I_DIM * H_DIM;
        unsigned short* dst = dbt + (size_t)e * I_DIM * H_DIM;
        const int c0 = blockIdx.x * 32, r0 = blockIdx.y * 32;
#pragma unroll
        for (int i = 0; i < 4; i++)
            tile[ty * 4 + i][tx] = src[(size_t)(r0 + ty * 4 + i) * H_DIM + c0 + tx];
        __syncthreads();
#pragma unroll
        for (int i = 0; i < 4; i++)
            dst[(size_t)(c0 + ty * 4 + i) * I_DIM + r0 + tx] = f2bf(tile[tx][ty * 4 + i]);
    }
}

// ---- router phase A: logits + top2 ----
__global__ void k_router_a(const float* __restrict__ x, const float* __restrict__ rw,
                           const float* __restrict__ rb,
                           int* __restrict__ top2e, float2* __restrict__ top2w) {
    const int wave = threadIdx.x >> 6, lane = threadIdx.x & 63;
    const int t = blockIdx.x * 4 + wave;
    const float* xr = x + (size_t)t * H_DIM;
    float acc[N_EXP];
#pragma unroll
    for (int e = 0; e < N_EXP; e++) acc[e] = 0.f;
#pragma unroll
    for (int j = 0; j < H_DIM / 256; j++) {
        int idx = j * 256 + lane * 4;
        float4 xv = *(const float4*)(xr + idx);
#pragma unroll
        for (int e = 0; e < N_EXP; e++) {
            float4 wv = *(const float4*)(rw + e * H_DIM + idx);
            acc[e] += xv.x * wv.x + xv.y * wv.y + xv.z * wv.z + xv.w * wv.w;
        }
    }
#pragma unroll
    for (int s = 32; s > 0; s >>= 1) {
#pragma unroll
        for (int e = 0; e < N_EXP; e++) acc[e] += __shfl_down(acc[e], s);
    }
    if (lane == 0) {
        float l[N_EXP];
#pragma unroll
        for (int e = 0; e < N_EXP; e++) l[e] = acc[e] + rb[e];
        int i1 = 0;
#pragma unroll
        for (int e = 1; e < N_EXP; e++) if (l[e] > l[i1]) i1 = e;
        int i2 = (i1 == 0) ? 1 : 0;
#pragma unroll
        for (int e = 0; e < N_EXP; e++) if (e != i1 && l[e] > l[i2]) i2 = e;
        float w1 = 1.f / (1.f + __expf(l[i2] - l[i1]));
        top2e[t] = i1 | (i2 << 8);
        top2w[t] = make_float2(w1, 1.f - w1);
    }
}

// ---- router phase B: block-aggregated list build; slot bit in tokslot bit16 ----
__global__ void k_router_b(const int* __restrict__ top2e, const float2* __restrict__ top2w,
                           int* __restrict__ cnt, int* __restrict__ tokslot,
                           float* __restrict__ pweight) {
    __shared__ int lcnt[N_EXP], lbase[N_EXP];
    const int tid = threadIdx.x;
    if (tid < N_EXP) lcnt[tid] = 0;
    __syncthreads();
    const int t = blockIdx.x * 256 + tid;
    const int pe = top2e[t];
    const float2 wv = top2w[t];
    const int e1 = pe & 0xff, e2 = pe >> 8;
    const int s1 = atomicAdd(&lcnt[e1], 1);
    const int s2 = atomicAdd(&lcnt[e2], 1);
    __syncthreads();
    if (tid < N_EXP) lbase[tid] = atomicAdd(&cnt[tid], lcnt[tid]);
    __syncthreads();
    const int p1 = lbase[e1] + s1;
    tokslot[e1 * T_TOK + p1] = t; pweight[e1 * T_TOK + p1] = wv.x;
    const int p2 = lbase[e2] + s2;
    tokslot[e2 * T_TOK + p2] = t | (1 << 16); pweight[e2 * T_TOK + p2] = wv.y;
}

// ---- build compact tile list: (expert, m0, dense_row_offset, cnt_e) ----
__global__ void k_tiles(const int* __restrict__ cnt, int4* __restrict__ tiles) {
    const int tid = threadIdx.x;
    if (tid < MAXTILE) tiles[tid] = make_int4(-1, 0, 0, 0);
    __syncthreads();
    if (tid == 0) {
        int off = 0, idx = 0;
        for (int e = 0; e < N_EXP; e++) {
            int cn = cnt[e];
            for (int m0 = 0; m0 < cn; m0 += 128)
                tiles[idx++] = make_int4(e, m0, off, cn);
            off += cn;
        }
    }
}

// ---- gather: x rows -> dense bf16 xg; pwg; inverse map for combine ----
__global__ void k_gather(const float* __restrict__ x, const int4* __restrict__ tiles,
                         const int* __restrict__ tokslot, const float* __restrict__ pweight,
                         unsigned short* __restrict__ xg, float* __restrict__ pwg,
                         int* __restrict__ inv) {
    const int4 td = tiles[blockIdx.x];
    const int e = td.x;
    if (e < 0) return;
    const int m0 = td.y, offe = td.z, cn = td.w;
    const int tid = threadIdx.x;
    // 128 rows x 96 chunks of 8 elements
    for (int c = tid; c < 128 * 96; c += 256) {
        int row = c / 96, col = (c % 96) * 8;
        int gr = m0 + row;
        if (gr >= cn) continue;
        int v = tokslot[e * T_TOK + gr];
        int tok = v & 0xFFFF;
        const float* src = x + (size_t)tok * H_DIM + col;
        float4 a = *(const float4*)src, b = *(const float4*)(src + 4);
        ushort4 o0; o0.x = f2bf(a.x); o0.y = f2bf(a.y); o0.z = f2bf(a.z); o0.w = f2bf(a.w);
        ushort4 o1; o1.x = f2bf(b.x); o1.y = f2bf(b.y); o1.z = f2bf(b.z); o1.w = f2bf(b.w);
        unsigned short* dst = xg + (size_t)(offe + gr) * H_DIM + col;
        *(ushort4*)dst = o0; *(ushort4*)(dst + 4) = o1;
        if ((c % 96) == 0) {
            pwg[offe + gr] = pweight[e * T_TOK + gr];
            inv[tok * 2 + ((v >> 16) & 1)] = offe + gr;
        }
    }
}

// ---- gate+up fused GEMM, m97 2x2-wave structure, dense A ----
__launch_bounds__(256, 4)
__global__ void k_gateup(const unsigned short* __restrict__ xg,
                         const unsigned short* __restrict__ wbt,
                         const int4* __restrict__ tiles,
                         const float* __restrict__ pwg,
                         unsigned short* __restrict__ hbuf) {
    const int4 td = tiles[blockIdx.x];
    const int e = td.x;
    if (e < 0) return;
    const int m0 = td.y, offe = td.z, cn = td.w;
    const int n0 = blockIdx.y * 64;   // actual I columns [n0, n0+64)

    __shared__ __align__(16) unsigned short ldsA[128 * 32];
    __shared__ __align__(16) unsigned short ldsB[128 * 32];
    __shared__ float pwLds[128];

    const int tid = threadIdx.x;
    if (tid < 128) pwLds[tid] = pwg[offe + m0 + tid];   // padded alloc; invalid rows guarded later
    __syncthreads();

    const int lane = tid & 63;
    const int wave = tid >> 6;
    const int fm = lane & 15, quad = lane >> 4;

    const int srow = wave * 16 + (lane >> 2);   // 0..63
    const int scol = (lane & 3) * 8;
    const unsigned short* aG1 = xg + (size_t)(offe + m0 + srow) * H_DIM + scol;
    const unsigned short* aG2 = aG1 + (size_t)64 * H_DIM;
    const unsigned short* bG1 = wbt + ((size_t)e * 2 * I_DIM + n0 * 2 + srow) * H_DIM + scol;
    const unsigned short* bG2 = bG1 + (size_t)64 * H_DIM;
    unsigned short* lA1 = ldsA + wave * 512;
    unsigned short* lA2 = ldsA + 2048 + wave * 512;
    unsigned short* lB1 = ldsB + wave * 512;
    unsigned short* lB2 = ldsB + 2048 + wave * 512;

    const int wm = (wave & 1) * 64, wnw = wave >> 1;

    v4f acc[4][4];
#pragma unroll
    for (int i = 0; i < 4; i++)
#pragma unroll
        for (int j = 0; j < 4; j++) acc[i][j] = (v4f)0.f;

    for (int kb = 0; kb < H_DIM / 32; kb++) {
        const int k0 = kb * 32;
        async16(aG1 + k0, lA1);
        async16(aG2 + k0, lA2);
        async16(bG1 + k0, lB1);
        async16(bG2 + k0, lB2);
        __syncthreads();
        v8s aF[4], bF[4];
#pragma unroll
        for (int im = 0; im < 4; im++)
            aF[im] = *(const v8s*)&ldsA[(wm + im * 16 + fm) * 32 + quad * 8];
#pragma unroll
        for (int in = 0; in < 4; in++)
            bF[in] = *(const v8s*)&ldsB[(wnw * 64 + in * 16 + fm) * 32 + quad * 8];
#pragma unroll
        for (int im = 0; im < 4; im++)
#pragma unroll
            for (int in = 0; in < 4; in++)
                acc[im][in] = __builtin_amdgcn_mfma_f32_16x16x32_bf16(aF[im], bF[in], acc[im][in], 0, 0, 0);
        __syncthreads();
    }

    // acc[im][2j]=gate, acc[im][2j+1]=up, cols n0 + wnw*32 + j*16 + fm
#pragma unroll
    for (int im = 0; im < 4; im++) {
#pragma unroll
        for (int reg = 0; reg < 4; reg++) {
            int lr = wm + im * 16 + quad * 4 + reg;
            int gr = m0 + lr;
            if (gr < cn) {
                float pw = pwLds[lr];
                size_t base = (size_t)(offe + gr) * I_DIM + n0 + wnw * 32 + fm;
#pragma unroll
                for (int j = 0; j < 2; j++) {
                    float g = acc[im][2 * j][reg];
                    float u = acc[im][2 * j + 1][reg];
                    float s = g / (1.f + __expf(-g));
                    hbuf[base + j * 16] = f2bf(s * u * pw);
                }
            }
        }
    }
}

// ---- down GEMM (m97 128x128), dense in, dense bf16 out ----
__launch_bounds__(256, 4)
__global__ void k_down(const unsigned short* __restrict__ hbuf,
                       const unsigned short* __restrict__ dbt,
                       const int4* __restrict__ tiles,
                       unsigned short* __restrict__ yd) {
    const int4 td = tiles[blockIdx.x];
    const int e = td.x;
    if (e < 0) return;
    const int m0 = td.y, offe = td.z, cn = td.w;
    const int n0 = blockIdx.y * 128;

    __shared__ __align__(16) unsigned short ldsA[128 * 32];
    __shared__ __align__(16) unsigned short ldsB[128 * 32];

    const int tid = threadIdx.x;
    const int lane = tid & 63;
    const int wave = tid >> 6;
    const int fm = lane & 15, quad = lane >> 4;

    const int srow = wave * 16 + (lane >> 2);
    const int scol = (lane & 3) * 8;
    const unsigned short* aG1 = hbuf + (size_t)(offe + m0 + srow) * I_DIM + scol;
    const unsigned short* aG2 = aG1 + (size_t)64 * I_DIM;
    const unsigned short* bG1 = dbt + ((size_t)e * H_DIM + n0 + srow) * I_DIM + scol;
    const unsigned short* bG2 = bG1 + (size_t)64 * I_DIM;
    unsigned short* lA1 = ldsA + wave * 512;
    unsigned short* lA2 = ldsA + 2048 + wave * 512;
    unsigned short* lB1 = ldsB + wave * 512;
    unsigned short* lB2 = ldsB + 2048 + wave * 512;

    const int wm = (wave & 1) * 64, wn = (wave >> 1) * 64;

    v4f acc[4][4];
#pragma unroll
    for (int i = 0; i < 4; i++)
#pragma unroll
        for (int j = 0; j < 4; j++) acc[i][j] = (v4f)0.f;

    for (int kb = 0; kb < I_DIM / 32; kb++) {
        const int k0 = kb * 32;
        async16(aG1 + k0, lA1);
        async16(aG2 + k0, lA2);
        async16(bG1 + k0, lB1);
        async16(bG2 + k0, lB2);
        __syncthreads();
        v8s aF[4], bF[4];
#pragma unroll
        for (int im = 0; im < 4; im++)
            aF[im] = *(const v8s*)&ldsA[(wm + im * 16 + fm) * 32 + quad * 8];
#pragma unroll
        for (int in = 0; in < 4; in++)
            bF[in] = *(const v8s*)&ldsB[(wn + in * 16 + fm) * 32 + quad * 8];
#pragma unroll
        for (int im = 0; im < 4; im++)
#pragma unroll
            for (int in = 0; in < 4; in++)
                acc[im][in] = __builtin_amdgcn_mfma_f32_16x16x32_bf16(aF[im], bF[in], acc[im][in], 0, 0, 0);
        __syncthreads();
    }

#pragma unroll
    for (int im = 0; im < 4; im++) {
#pragma unroll
        for (int reg = 0; reg < 4; reg++) {
            int lr = wm + im * 16 + quad * 4 + reg;
            int gr = m0 + lr;
            if (gr < cn) {
#pragma unroll
                for (int in = 0; in < 4; in++) {
                    int col = n0 + wn + in * 16 + fm;
                    yd[(size_t)(offe + gr) * H_DIM + col] = f2bf(acc[im][in][reg]);
                }
            }
        }
    }
}

// ---- combine: out[t] = yd[inv[2t]] + yd[inv[2t+1]], fp32 out; wave per token ----
__global__ void k_combine(const unsigned short* __restrict__ yd, const int* __restrict__ inv,
                          float* __restrict__ out) {
    const int wave = threadIdx.x >> 6, lane = threadIdx.x & 63;
    const int t = blockIdx.x * 4 + wave;
    const unsigned short* y0 = yd + (size_t)inv[2 * t] * H_DIM;
    const unsigned short* y1 = yd + (size_t)inv[2 * t + 1] * H_DIM;
    float* o = out + (size_t)t * H_DIM;
#pragma unroll
    for (int j = 0; j < 3; j++) {
        int idx = j * 256 + lane * 4;
        ushort4 a = *(const ushort4*)(y0 + idx);
        ushort4 b = *(const ushort4*)(y1 + idx);
        float4 v;
        v.x = bf2f(a.x) + bf2f(b.x); v.y = bf2f(a.y) + bf2f(b.y);
        v.z = bf2f(a.z) + bf2f(b.z); v.w = bf2f(a.w) + bf2f(b.w);
        *(float4*)(o + idx) = v;
    }
}

extern "C" void kernel_launch(void* const* d_in, const int* in_sizes, int n_in,
                              void* d_out, int out_size, void* d_ws, size_t ws_size,
                              hipStream_t stream) {
    const float* x  = (const float*)d_in[0];
    const float* rw = (const float*)d_in[1];
    const float* rb = (const float*)d_in[2];
    const float* gw = (const float*)d_in[3];
    const float* uw = (const float*)d_in[4];
    const float* dw = (const float*)d_in[5];
    float* out = (float*)d_out;

    char* ws = (char*)d_ws;
    size_t o = 0;
    auto alloc = [&](size_t bytes) { void* p = ws + o; o += (bytes + 255) & ~255ull; return p; };
    int*    cnt     = (int*)   alloc(N_EXP * 4);
    int*    tokslot = (int*)   alloc((size_t)N_EXP * T_TOK * 4);
    float*  pweight = (float*) alloc((size_t)N_EXP * T_TOK * 4);
    int*    top2e   = (int*)   alloc((size_t)T_TOK * 4);
    float2* top2w   = (float2*)alloc((size_t)T_TOK * 8);
    int4*   tiles   = (int4*)  alloc((size_t)MAXTILE * 16);
    float*  pwg     = (float*) alloc((size_t)(DROWS + 128) * 4);
    int*    inv     = (int*)   alloc((size_t)T_TOK * 2 * 4);
    unsigned short* wbt  = (unsigned short*)alloc((size_t)N_EXP * 2 * I_DIM * H_DIM * 2);
    unsigned short* dbt  = (unsigned short*)alloc((size_t)N_EXP * H_DIM * I_DIM * 2);
    unsigned short* xg   = (unsigned short*)alloc((size_t)(DROWS + 128) * H_DIM * 2);
    unsigned short* hbuf = (unsigned short*)alloc((size_t)(DROWS + 128) * I_DIM * 2);
    unsigned short* yd   = (unsigned short*)alloc((size_t)DROWS * H_DIM * 2);

    hipMemsetAsync(cnt, 0, N_EXP * 4, stream);

    dim3 tg(I_DIM / 32, I_DIM / 32, 3 * N_EXP);
    k_transp_all<<<tg, dim3(32, 8), 0, stream>>>(gw, uw, dw, wbt, dbt);

    k_router_a<<<T_TOK / 4, 256, 0, stream>>>(x, rw, rb, top2e, top2w);
    k_router_b<<<T_TOK / 256, 256, 0, stream>>>(top2e, top2w, cnt, tokslot, pweight);
    k_tiles<<<1, 256, 0, stream>>>(cnt, tiles);
    k_gather<<<MAXTILE, 256, 0, stream>>>(x, tiles, tokslot, pweight, xg, pwg, inv);

    dim3 g1(MAXTILE, I_DIM / 64);
    k_gateup<<<g1, 256, 0, stream>>>(xg, wbt, tiles, pwg, hbuf);

    dim3 g2(MAXTILE, H_DIM / 128);
    k_down<<<g2, 256, 0, stream>>>(hbuf, dbt, tiles, yd);

    k_combine<<<T_TOK / 4, 256, 0, stream>>>(yd, inv, out);
}

// Round 6
// 263.982 us; speedup vs baseline: 1.1344x; 1.1344x over previous
//
#include <hip/hip_runtime.h>
#include <hip/hip_bf16.h>
#include <cstdint>
#include <cstddef>

#define T_TOK 8192
#define H_DIM 768
#define I_DIM 1024
#define N_EXP 5
#define MAXTILE 136

typedef short v8s __attribute__((ext_vector_type(8)));
typedef float v4f __attribute__((ext_vector_type(4)));

static __device__ __forceinline__ unsigned short f2bf(float f) {
    union { float f; unsigned int u; } v; v.f = f;
    unsigned int u = v.u;
    unsigned int r = (u + 0x7fffu + ((u >> 16) & 1u)) >> 16;
    return (unsigned short)r;
}
static __device__ __forceinline__ float bf2f(unsigned short s) {
    union { unsigned int u; float f; } v; v.u = ((unsigned int)s) << 16; return v.f;
}

// async 16B global->LDS (wave-uniform LDS base + lane*16)
static __device__ __forceinline__ void async16(const unsigned short* g, unsigned short* l) {
    __builtin_amdgcn_global_load_lds(
        (const __attribute__((address_space(1))) unsigned int*)g,
        (__attribute__((address_space(3))) unsigned int*)l, 16, 0, 0);
}

// ---- merged weight transposes (float4 loads, ushort4 stores) ----
// z in [0,10): gate/up [e][H][I] -> wbt[e][2I][H], interleaved by 16-col groups
// z in [10,15): down  [e][I][H] -> dbt[e][H][I]
__global__ void k_transp_all(const float* __restrict__ gw, const float* __restrict__ uw,
                             const float* __restrict__ dw,
                             unsigned short* __restrict__ wbt, unsigned short* __restrict__ dbt) {
    __shared__ float tile[32][33];
    const int z = blockIdx.z;
    const int tid = threadIdx.x;
    const int row = tid >> 3, cq = tid & 7;       // load: 32 rows x 8 float4
    const int ocol = tid >> 3, seg = tid & 7;     // store: 32 cols x 8 ushort4
    if (z < 2 * N_EXP) {
        if (blockIdx.y >= H_DIM / 32) return;
        const int e = z % N_EXP;
        const int isUp = z >= N_EXP;
        const float* src = (isUp ? uw : gw) + (size_t)e * H_DIM * I_DIM;
        const int c0 = blockIdx.x * 32, r0 = blockIdx.y * 32;
        float4 v = *(const float4*)(src + (size_t)(r0 + row) * I_DIM + c0 + cq * 4);
        tile[row][cq * 4 + 0] = v.x; tile[row][cq * 4 + 1] = v.y;
        tile[row][cq * 4 + 2] = v.z; tile[row][cq * 4 + 3] = v.w;
        __syncthreads();
        int c = c0 + ocol;
        int orow = (c >> 4) * 32 + (c & 15) + (isUp ? 16 : 0);
        ushort4 o;
        o.x = f2bf(tile[seg * 4 + 0][ocol]); o.y = f2bf(tile[seg * 4 + 1][ocol]);
        o.z = f2bf(tile[seg * 4 + 2][ocol]); o.w = f2bf(tile[seg * 4 + 3][ocol]);
        *(ushort4*)(wbt + ((size_t)e * 2 * I_DIM + orow) * H_DIM + r0 + seg * 4) = o;
    } else {
        if (blockIdx.x >= H_DIM / 32) return;
        const int e = z - 2 * N_EXP;
        const float* src = dw + (size_t)e * I_DIM * H_DIM;
        unsigned short* dst = dbt + (size_t)e * I_DIM * H_DIM;
        const int c0 = blockIdx.x * 32, r0 = blockIdx.y * 32;
        float4 v = *(const float4*)(src + (size_t)(r0 + row) * H_DIM + c0 + cq * 4);
        tile[row][cq * 4 + 0] = v.x; tile[row][cq * 4 + 1] = v.y;
        tile[row][cq * 4 + 2] = v.z; tile[row][cq * 4 + 3] = v.w;
        __syncthreads();
        ushort4 o;
        o.x = f2bf(tile[seg * 4 + 0][ocol]); o.y = f2bf(tile[seg * 4 + 1][ocol]);
        o.z = f2bf(tile[seg * 4 + 2][ocol]); o.w = f2bf(tile[seg * 4 + 3][ocol]);
        *(ushort4*)(dst + (size_t)(c0 + ocol) * I_DIM + r0 + seg * 4) = o;
    }
}

// ---- router phase A: logits + top2 + fused x->bf16 convert ----
__global__ void k_router_a(const float* __restrict__ x, const float* __restrict__ rw,
                           const float* __restrict__ rb,
                           unsigned short* __restrict__ xb,
                           int* __restrict__ top2e, float2* __restrict__ top2w) {
    const int wave = threadIdx.x >> 6, lane = threadIdx.x & 63;
    const int t = blockIdx.x * 4 + wave;
    const float* xr = x + (size_t)t * H_DIM;
    unsigned short* xbr = xb + (size_t)t * H_DIM;
    float acc[N_EXP];
#pragma unroll
    for (int e = 0; e < N_EXP; e++) acc[e] = 0.f;
#pragma unroll
    for (int j = 0; j < H_DIM / 256; j++) {
        int idx = j * 256 + lane * 4;
        float4 xv = *(const float4*)(xr + idx);
        ushort4 o;
        o.x = f2bf(xv.x); o.y = f2bf(xv.y); o.z = f2bf(xv.z); o.w = f2bf(xv.w);
        *(ushort4*)(xbr + idx) = o;
#pragma unroll
        for (int e = 0; e < N_EXP; e++) {
            float4 wv = *(const float4*)(rw + e * H_DIM + idx);
            acc[e] += xv.x * wv.x + xv.y * wv.y + xv.z * wv.z + xv.w * wv.w;
        }
    }
#pragma unroll
    for (int s = 32; s > 0; s >>= 1) {
#pragma unroll
        for (int e = 0; e < N_EXP; e++) acc[e] += __shfl_down(acc[e], s);
    }
    if (lane == 0) {
        float l[N_EXP];
#pragma unroll
        for (int e = 0; e < N_EXP; e++) l[e] = acc[e] + rb[e];
        int i1 = 0;
#pragma unroll
        for (int e = 1; e < N_EXP; e++) if (l[e] > l[i1]) i1 = e;
        int i2 = (i1 == 0) ? 1 : 0;
#pragma unroll
        for (int e = 0; e < N_EXP; e++) if (e != i1 && l[e] > l[i2]) i2 = e;
        float w1 = 1.f / (1.f + __expf(l[i2] - l[i1]));
        top2e[t] = i1 | (i2 << 8);
        top2w[t] = make_float2(w1, 1.f - w1);
    }
}

// ---- router phase B: block-aggregated list build; slot bit in tokslot bit16 ----
__global__ void k_router_b(const int* __restrict__ top2e, const float2* __restrict__ top2w,
                           int* __restrict__ cnt, int* __restrict__ tokslot,
                           float* __restrict__ pweight) {
    __shared__ int lcnt[N_EXP], lbase[N_EXP];
    const int tid = threadIdx.x;
    if (tid < N_EXP) lcnt[tid] = 0;
    __syncthreads();
    const int t = blockIdx.x * 256 + tid;
    const int pe = top2e[t];
    const float2 wv = top2w[t];
    const int e1 = pe & 0xff, e2 = pe >> 8;
    const int s1 = atomicAdd(&lcnt[e1], 1);
    const int s2 = atomicAdd(&lcnt[e2], 1);
    __syncthreads();
    if (tid < N_EXP) lbase[tid] = atomicAdd(&cnt[tid], lcnt[tid]);
    __syncthreads();
    const int p1 = lbase[e1] + s1;
    tokslot[e1 * T_TOK + p1] = t; pweight[e1 * T_TOK + p1] = wv.x;
    const int p2 = lbase[e2] + s2;
    tokslot[e2 * T_TOK + p2] = t | (1 << 16); pweight[e2 * T_TOK + p2] = wv.y;
}

// ---- build compact tile list: (expert, m0, dense_row_offset, cnt_e) ----
__global__ void k_tiles(const int* __restrict__ cnt, int4* __restrict__ tiles) {
    const int tid = threadIdx.x;
    if (tid < MAXTILE) tiles[tid] = make_int4(-1, 0, 0, 0);
    __syncthreads();
    if (tid == 0) {
        int off = 0, idx = 0;
        for (int e = 0; e < N_EXP; e++) {
            int cn = cnt[e];
            for (int m0 = 0; m0 < cn; m0 += 128)
                tiles[idx++] = make_int4(e, m0, off, cn);
            off += cn;
        }
    }
}

// ---- gate+up fused GEMM, m97 2x2-wave structure + bank-conflict swizzle ----
// LDS chunk swizzle: physical chunk pc at row r holds logical chunk (pc - (r>>1))&3.
// Staged on the GLOBAL side (fetch logical chunk lc = ((lane&3)-(srow>>1))&3);
// fragments read physical pq = (quad + (fm>>1))&3.
__launch_bounds__(256, 4)
__global__ void k_gateup(const unsigned short* __restrict__ xb,
                         const unsigned short* __restrict__ wbt,
                         const int4* __restrict__ tiles,
                         const int* __restrict__ tokslot,
                         const float* __restrict__ pweight,
                         unsigned short* __restrict__ hbuf) {
    const int4 td = tiles[blockIdx.x];
    const int e = td.x;
    if (e < 0) return;
    const int m0 = td.y, offe = td.z, cn = td.w;
    const int n0 = blockIdx.y * 64;   // actual I columns [n0, n0+64)

    __shared__ __align__(16) unsigned short ldsA[128 * 32];
    __shared__ __align__(16) unsigned short ldsB[128 * 32];
    __shared__ int tokLds[128];
    __shared__ float pwLds[128];

    const int tid = threadIdx.x;
    if (tid < 128) {
        int gr = m0 + tid;
        int tk = 0; float pw = 0.f;
        if (gr < cn) { tk = tokslot[e * T_TOK + gr] & 0xFFFF; pw = pweight[e * T_TOK + gr]; }
        tokLds[tid] = tk; pwLds[tid] = pw;
    }
    __syncthreads();

    const int lane = tid & 63;
    const int wave = tid >> 6;
    const int fm = lane & 15, quad = lane >> 4;
    const int pq = (quad + (fm >> 1)) & 3;   // swizzled physical chunk for fragment reads

    const int srow = wave * 16 + (lane >> 2);                 // 0..63
    const int scol = (((lane & 3) - (srow >> 1)) & 3) * 8;    // swizzled logical chunk
    const unsigned short* aG1 = xb + (size_t)tokLds[srow] * H_DIM + scol;
    const unsigned short* aG2 = xb + (size_t)tokLds[64 + srow] * H_DIM + scol;
    const unsigned short* bG1 = wbt + ((size_t)e * 2 * I_DIM + n0 * 2 + srow) * H_DIM + scol;
    const unsigned short* bG2 = bG1 + (size_t)64 * H_DIM;
    unsigned short* lA1 = ldsA + wave * 512;
    unsigned short* lA2 = ldsA + 2048 + wave * 512;
    unsigned short* lB1 = ldsB + wave * 512;
    unsigned short* lB2 = ldsB + 2048 + wave * 512;

    const int wm = (wave & 1) * 64, wnw = wave >> 1;

    v4f acc[4][4];
#pragma unroll
    for (int i = 0; i < 4; i++)
#pragma unroll
        for (int j = 0; j < 4; j++) acc[i][j] = (v4f)0.f;

    for (int kb = 0; kb < H_DIM / 32; kb++) {
        const int k0 = kb * 32;
        async16(aG1 + k0, lA1);
        async16(aG2 + k0, lA2);
        async16(bG1 + k0, lB1);
        async16(bG2 + k0, lB2);
        __syncthreads();
        v8s aF[4], bF[4];
#pragma unroll
        for (int im = 0; im < 4; im++)
            aF[im] = *(const v8s*)&ldsA[(wm + im * 16 + fm) * 32 + pq * 8];
#pragma unroll
        for (int in = 0; in < 4; in++)
            bF[in] = *(const v8s*)&ldsB[(wnw * 64 + in * 16 + fm) * 32 + pq * 8];
#pragma unroll
        for (int im = 0; im < 4; im++)
#pragma unroll
            for (int in = 0; in < 4; in++)
                acc[im][in] = __builtin_amdgcn_mfma_f32_16x16x32_bf16(aF[im], bF[in], acc[im][in], 0, 0, 0);
        __syncthreads();
    }

    // acc[im][2j]=gate, acc[im][2j+1]=up, cols n0 + wnw*32 + j*16 + fm
#pragma unroll
    for (int im = 0; im < 4; im++) {
#pragma unroll
        for (int reg = 0; reg < 4; reg++) {
            int lr = wm + im * 16 + quad * 4 + reg;
            int gr = m0 + lr;
            if (gr < cn) {
                float pw = pwLds[lr];
                size_t base = (size_t)(offe + gr) * I_DIM + n0 + wnw * 32 + fm;
#pragma unroll
                for (int j = 0; j < 2; j++) {
                    float g = acc[im][2 * j][reg];
                    float u = acc[im][2 * j + 1][reg];
                    float s = g / (1.f + __expf(-g));
                    hbuf[base + j * 16] = f2bf(s * u * pw);
                }
            }
        }
    }
}

// ---- down GEMM (m97 128x128 + swizzle), bf16 stores into ybuf[slot][tok][H] ----
__launch_bounds__(256, 4)
__global__ void k_down(const unsigned short* __restrict__ hbuf,
                       const unsigned short* __restrict__ dbt,
                       const int4* __restrict__ tiles,
                       const int* __restrict__ tokslot,
                       unsigned short* __restrict__ ybuf) {
    const int4 td = tiles[blockIdx.x];
    const int e = td.x;
    if (e < 0) return;
    const int m0 = td.y, offe = td.z, cn = td.w;
    const int n0 = blockIdx.y * 128;

    __shared__ __align__(16) unsigned short ldsA[128 * 32];
    __shared__ __align__(16) unsigned short ldsB[128 * 32];
    __shared__ int tokLds[128];

    const int tid = threadIdx.x;
    if (tid < 128) {
        int gr = m0 + tid;
        tokLds[tid] = (gr < cn) ? tokslot[e * T_TOK + gr] : 0;
    }
    __syncthreads();

    const int lane = tid & 63;
    const int wave = tid >> 6;
    const int fm = lane & 15, quad = lane >> 4;
    const int pq = (quad + (fm >> 1)) & 3;

    const int srow = wave * 16 + (lane >> 2);
    const int scol = (((lane & 3) - (srow >> 1)) & 3) * 8;
    int ar1 = m0 + srow;      if (ar1 >= cn) ar1 = cn - 1;
    int ar2 = m0 + 64 + srow; if (ar2 >= cn) ar2 = cn - 1;
    const unsigned short* aG1 = hbuf + (size_t)(offe + ar1) * I_DIM + scol;
    const unsigned short* aG2 = hbuf + (size_t)(offe + ar2) * I_DIM + scol;
    const unsigned short* bG1 = dbt + ((size_t)e * H_DIM + n0 + srow) * I_DIM + scol;
    const unsigned short* bG2 = bG1 + (size_t)64 * I_DIM;
    unsigned short* lA1 = ldsA + wave * 512;
    unsigned short* lA2 = ldsA + 2048 + wave * 512;
    unsigned short* lB1 = ldsB + wave * 512;
    unsigned short* lB2 = ldsB + 2048 + wave * 512;

    const int wm = (wave & 1) * 64, wn = (wave >> 1) * 64;

    v4f acc[4][4];
#pragma unroll
    for (int i = 0; i < 4; i++)
#pragma unroll
        for (int j = 0; j < 4; j++) acc[i][j] = (v4f)0.f;

    for (int kb = 0; kb < I_DIM / 32; kb++) {
        const int k0 = kb * 32;
        async16(aG1 + k0, lA1);
        async16(aG2 + k0, lA2);
        async16(bG1 + k0, lB1);
        async16(bG2 + k0, lB2);
        __syncthreads();
        v8s aF[4], bF[4];
#pragma unroll
        for (int im = 0; im < 4; im++)
            aF[im] = *(const v8s*)&ldsA[(wm + im * 16 + fm) * 32 + pq * 8];
#pragma unroll
        for (int in = 0; in < 4; in++)
            bF[in] = *(const v8s*)&ldsB[(wn + in * 16 + fm) * 32 + pq * 8];
#pragma unroll
        for (int im = 0; im < 4; im++)
#pragma unroll
            for (int in = 0; in < 4; in++)
                acc[im][in] = __builtin_amdgcn_mfma_f32_16x16x32_bf16(aF[im], bF[in], acc[im][in], 0, 0, 0);
        __syncthreads();
    }

#pragma unroll
    for (int im = 0; im < 4; im++) {
#pragma unroll
        for (int reg = 0; reg < 4; reg++) {
            int lr = wm + im * 16 + quad * 4 + reg;
            int gr = m0 + lr;
            if (gr < cn) {
                int v = tokLds[lr];
                int tok = v & 0xFFFF, s = (v >> 16) & 1;
#pragma unroll
                for (int in = 0; in < 4; in++) {
                    int col = n0 + wn + in * 16 + fm;
                    ybuf[((size_t)s * T_TOK + tok) * H_DIM + col] = f2bf(acc[im][in][reg]);
                }
            }
        }
    }
}

// ---- combine: out = ybuf[0] + ybuf[1], fp32 out ----
__global__ void k_combine(const unsigned short* __restrict__ ybuf, float* __restrict__ out) {
    const size_t i8 = ((size_t)blockIdx.x * 256 + threadIdx.x) * 8;
    const unsigned short* y0 = ybuf + i8;
    const unsigned short* y1 = ybuf + (size_t)T_TOK * H_DIM + i8;
    ushort4 a0 = *(const ushort4*)y0, a1 = *(const ushort4*)(y0 + 4);
    ushort4 b0 = *(const ushort4*)y1, b1 = *(const ushort4*)(y1 + 4);
    float4 o0, o1;
    o0.x = bf2f(a0.x) + bf2f(b0.x); o0.y = bf2f(a0.y) + bf2f(b0.y);
    o0.z = bf2f(a0.z) + bf2f(b0.z); o0.w = bf2f(a0.w) + bf2f(b0.w);
    o1.x = bf2f(a1.x) + bf2f(b1.x); o1.y = bf2f(a1.y) + bf2f(b1.y);
    o1.z = bf2f(a1.z) + bf2f(b1.z); o1.w = bf2f(a1.w) + bf2f(b1.w);
    *(float4*)(out + i8) = o0;
    *(float4*)(out + i8 + 4) = o1;
}

extern "C" void kernel_launch(void* const* d_in, const int* in_sizes, int n_in,
                              void* d_out, int out_size, void* d_ws, size_t ws_size,
                              hipStream_t stream) {
    const float* x  = (const float*)d_in[0];
    const float* rw = (const float*)d_in[1];
    const float* rb = (const float*)d_in[2];
    const float* gw = (const float*)d_in[3];
    const float* uw = (const float*)d_in[4];
    const float* dw = (const float*)d_in[5];
    float* out = (float*)d_out;

    char* ws = (char*)d_ws;
    size_t o = 0;
    auto alloc = [&](size_t bytes) { void* p = ws + o; o += (bytes + 255) & ~255ull; return p; };
    int*    cnt     = (int*)   alloc(N_EXP * 4);
    int*    tokslot = (int*)   alloc((size_t)N_EXP * T_TOK * 4);
    float*  pweight = (float*) alloc((size_t)N_EXP * T_TOK * 4);
    int*    top2e   = (int*)   alloc((size_t)T_TOK * 4);
    float2* top2w   = (float2*)alloc((size_t)T_TOK * 8);
    int4*   tiles   = (int4*)  alloc((size_t)MAXTILE * 16);
    unsigned short* xb   = (unsigned short*)alloc((size_t)T_TOK * H_DIM * 2);
    unsigned short* wbt  = (unsigned short*)alloc((size_t)N_EXP * 2 * I_DIM * H_DIM * 2);
    unsigned short* dbt  = (unsigned short*)alloc((size_t)N_EXP * H_DIM * I_DIM * 2);
    unsigned short* hbuf = (unsigned short*)alloc((size_t)(2 * T_TOK + 128) * I_DIM * 2);
    unsigned short* ybuf = (unsigned short*)alloc((size_t)2 * T_TOK * H_DIM * 2);

    hipMemsetAsync(cnt, 0, N_EXP * 4, stream);

    dim3 tg(I_DIM / 32, I_DIM / 32, 3 * N_EXP);
    k_transp_all<<<tg, 256, 0, stream>>>(gw, uw, dw, wbt, dbt);

    k_router_a<<<T_TOK / 4, 256, 0, stream>>>(x, rw, rb, xb, top2e, top2w);
    k_router_b<<<T_TOK / 256, 256, 0, stream>>>(top2e, top2w, cnt, tokslot, pweight);
    k_tiles<<<1, 256, 0, stream>>>(cnt, tiles);

    dim3 g1(MAXTILE, I_DIM / 64);
    k_gateup<<<g1, 256, 0, stream>>>(xb, wbt, tiles, tokslot, pweight, hbuf);

    dim3 g2(MAXTILE, H_DIM / 128);
    k_down<<<g2, 256, 0, stream>>>(hbuf, dbt, tiles, tokslot, ybuf);

    k_combine<<<(T_TOK * H_DIM) / (256 * 8), 256, 0, stream>>>(ybuf, out);
}